// Round 24
// baseline (432.550 us; speedup 1.0000x reference)
//
#include <hip/hip_runtime.h>
#include <math.h>

#define DI __device__ __forceinline__

// PL=8 LAT=96 LON=180 C=192 H=6 D=32 ; windows (2,6,12) shift (1,3,6)
// NPL=4 NLAT=16 NLON=15 NW=64 N=144 L=138240 ; BIAS_SIZE=3444
constexpr float QSCALE = 0.17677669529663687f; // 32^-0.5

typedef unsigned short bf16_t;
typedef __attribute__((ext_vector_type(8))) short short8;
typedef __attribute__((ext_vector_type(4))) short short4v;
typedef __attribute__((ext_vector_type(4))) float f32x4;

#if __has_builtin(__builtin_amdgcn_mfma_f32_16x16x16_bf16)
DI f32x4 MFMA16(short4v a, short4v b, f32x4 c) {
    return __builtin_amdgcn_mfma_f32_16x16x16_bf16(a, b, c, 0, 0, 0);
}
#elif __has_builtin(__builtin_amdgcn_mfma_f32_16x16x16bf16_1k)
DI f32x4 MFMA16(short4v a, short4v b, f32x4 c) {
    return __builtin_amdgcn_mfma_f32_16x16x16bf16_1k(a, b, c, 0, 0, 0);
}
#else
DI f32x4 MFMA16(short4v a, short4v b, f32x4 c) {
    asm volatile("v_mfma_f32_16x16x16_bf16 %0, %1, %2, %0"
                 : "+v"(c) : "v"(a), "v"(b));
    return c;
}
#endif

DI unsigned short f2b(float f) {            // fp32 -> bf16 bits, RNE
    unsigned u = __builtin_bit_cast(unsigned, f);
    return (unsigned short)((u + 0x7FFFu + ((u >> 16) & 1u)) >> 16);
}

// async global->LDS DMA, 16 B per lane, linear dest (wave base + lane*16)
DI void gload_lds16(const bf16_t* g, bf16_t* l) {
    __builtin_amdgcn_global_load_lds(
        (const __attribute__((address_space(1))) unsigned int*)(const void*)g,
        (__attribute__((address_space(3))) unsigned int*)(void*)l, 16, 0, 0);
}

// windowed row -> original token offset (*192), applying forward roll (-1,-3,-6)
DI int src_off(int row) {
    int bl  = row / 9216;  int rem = row - bl * 9216;   // 9216 = 64*144
    int wi  = rem / 144;   int n   = rem - wi * 144;
    int npl = wi >> 4,     nlat = wi & 15;
    int w0  = n / 72;      int rn = n - w0 * 72;
    int w1  = rn / 12;     int w2 = rn - w1 * 12;
    int pl = npl * 2 + w0 + 1;  if (pl >= 8)   pl -= 8;
    int la = nlat * 6 + w1 + 3; if (la >= 96)  la -= 96;
    int lo = bl * 12 + w2 + 6;  if (lo >= 180) lo -= 180;
    return ((pl * 96 + la) * 180 + lo) * 192;
}

DI int tiled_base(int row) {   // windowed row -> q/v tiled base (h,d added later)
    int bl = row / 9216; int rem = row - bl * 9216;
    int wi = rem / 144;  int n = rem - wi * 144;
    return bl * 1769472 + wi * 4608 + n * 32;
}

DI int k40_base(int row) {     // windowed row -> padded K tile base (stride 40)
    int bl = row / 9216; int rem = row - bl * 9216;
    int wi = rem / 144;  int n = rem - wi * 144;
    return bl * 2359296 + wi * 6144 + n * 40;   // bid*6144 + n*40 (h added later)
}

// fast GELU: x*sigmoid(1.595769x + 0.0713548x^3); |err| vs exact < ~1e-3
DI float gelu_fast(float x) {
    float t  = x * x;
    float in = __builtin_fmaf(t, 0.07135481283f, 1.5957691216f);
    float e  = __expf(-x * in);
    return x * __builtin_amdgcn_rcpf(1.0f + e);
}

// ---------------------------------------------------------------------------
// Fused prep: all weight conversions + bias transpose (padded 3584) in ONE.
// Ranges: wq 110592 | wpp 36864 | w1s 147456 | w2s 147456 | btT 1376256
// ---------------------------------------------------------------------------
__global__ __launch_bounds__(256) void prep_kernel(
    const float* __restrict__ qkvw, const float* __restrict__ projw,
    const float* __restrict__ fc1w, const float* __restrict__ fc2w,
    const float* __restrict__ biast,
    bf16_t* __restrict__ wq, bf16_t* __restrict__ wpp,
    bf16_t* __restrict__ w1s, bf16_t* __restrict__ w2s,
    float* __restrict__ btT)
{
    int i = blockIdx.x * 256 + threadIdx.x;
    if (i < 110592) {                       // qkv W: 18 chunks of 32 cols
        int fcol = i / 192, k = i - fcol * 192;
        int nc = fcol >> 5, row = fcol & 31;
        wq[nc * 6144 + row * 192 + (k ^ ((row & 7) << 3))] = f2b(qkvw[k * 576 + fcol]);
        return;
    }
    i -= 110592;
    if (i < 36864) {                        // proj W: 6 chunks
        int fcol = i / 192, k = i - fcol * 192;
        int nc = fcol >> 5, row = fcol & 31;
        wpp[nc * 6144 + row * 192 + (k ^ ((row & 7) << 3))] = f2b(projw[k * 192 + fcol]);
        return;
    }
    i -= 36864;
    if (i < 147456) {                       // fc1 W: 24 chunks
        int fcol = i / 192, k = i - fcol * 192;
        int nc = fcol >> 5, row = fcol & 31;
        w1s[nc * 6144 + row * 192 + (k ^ ((row & 7) << 3))] = f2b(fc1w[k * 768 + fcol]);
        return;
    }
    i -= 147456;
    if (i < 147456) {                       // fc2 W: 24 chunks, [g][ctA][r] perm
        int k = i / 192, col = i - k * 192;
        int nc = k >> 5, kl = k & 31;
        int ctA = kl >> 4, g = (kl >> 2) & 3, r = kl & 3;
        w2s[nc * 6144 + col * 32 + g * 8 + ctA * 4 + r] = f2b(fc2w[i]);
        return;
    }
    i -= 147456;
    if (i < 1376256) {                      // bias transpose, padded stride 3584
        int wh = i / 3584, e = i - wh * 3584;
        btT[i] = (e < 3444) ? biast[e * 384 + wh] : 0.0f;
    }
}

// ---------------------------------------------------------------------------
// QKV v3b: LN1 fused, A in regs; W chunks via DMA ping-pong. K output goes
// to padded per-window tiles (stride 40) so attn can DMA it linearly.
// ---------------------------------------------------------------------------
__global__ __launch_bounds__(256, 4) void qkv_mfma_kernel(
    const float* __restrict__ x,
    const float* __restrict__ ln1w, const float* __restrict__ ln1b,
    const bf16_t* __restrict__ wq,   // [18 chunks][6144] swizzled
    const float* __restrict__ bias,  // [576]
    bf16_t* __restrict__ qo, bf16_t* __restrict__ ko, bf16_t* __restrict__ vo)
{
    __shared__ bf16_t wbuf[2][6144];
    __shared__ float lw[192], lb[192], sbias[576];

    const int t  = threadIdx.x;
    const int m0 = blockIdx.x * 64;
    const int l = t & 63, wv = t >> 6;
    const int c = l & 15, g = l >> 4;
    const int soff = wv * 512 + l * 8;

    #pragma unroll
    for (int i = 0; i < 3; i++)
        gload_lds16(wq + i * 2048 + soff, wbuf[0] + i * 2048 + soff);

    for (int v = t; v < 192; v += 256) { lw[v] = ln1w[v]; lb[v] = ln1b[v]; }
    for (int v = t; v < 576; v += 256) sbias[v] = bias[v];

    const int msrc = src_off(m0 + 16 * wv + c);

    float fa[6][8];
    float ss = 0.f, s2 = 0.f;
    #pragma unroll
    for (int kc = 0; kc < 6; kc++) {
        float4 v0 = *(const float4*)(x + msrc + kc * 32 + 8 * g);
        float4 v1 = *(const float4*)(x + msrc + kc * 32 + 8 * g + 4);
        fa[kc][0]=v0.x; fa[kc][1]=v0.y; fa[kc][2]=v0.z; fa[kc][3]=v0.w;
        fa[kc][4]=v1.x; fa[kc][5]=v1.y; fa[kc][6]=v1.z; fa[kc][7]=v1.w;
        ss += v0.x+v0.y+v0.z+v0.w + v1.x+v1.y+v1.z+v1.w;
        s2 += v0.x*v0.x+v0.y*v0.y+v0.z*v0.z+v0.w*v0.w
            + v1.x*v1.x+v1.y*v1.y+v1.z*v1.z+v1.w*v1.w;
    }
    ss += __shfl_xor(ss, 16); s2 += __shfl_xor(s2, 16);
    ss += __shfl_xor(ss, 32); s2 += __shfl_xor(s2, 32);
    float mu = ss * (1.f / 192.f);
    float rs = 1.0f / sqrtf(s2 * (1.f / 192.f) - mu * mu + 1e-5f);
    __syncthreads();                        // lw/lb staged

    short8 a[6];
    #pragma unroll
    for (int kc = 0; kc < 6; kc++) {
        union { bf16_t e[8]; short8 v; } u;
        #pragma unroll
        for (int j = 0; j < 8; j++) {
            int col = kc * 32 + 8 * g + j;
            u.e[j] = f2b((fa[kc][j] - mu) * rs * lw[col] + lb[col]);
        }
        a[kc] = u.v;
    }

    int rb4[4], kb4[4];
    #pragma unroll
    for (int r = 0; r < 4; r++) {
        int row = m0 + 16 * wv + 4 * g + r;
        rb4[r] = tiled_base(row);
        kb4[r] = k40_base(row);
    }

    for (int nc = 0; nc < 18; nc++) {
        const int p = nc & 1;
        if (nc < 17) {
            #pragma unroll
            for (int i = 0; i < 3; i++)
                gload_lds16(wq + (nc + 1) * 6144 + i * 2048 + soff,
                            wbuf[p ^ 1] + i * 2048 + soff);
            asm volatile("s_waitcnt vmcnt(3)");   // drain chunk nc (+older ops)
        } else {
            asm volatile("s_waitcnt vmcnt(0)");
        }
        asm volatile("" ::: "memory");
        __builtin_amdgcn_s_barrier();
        asm volatile("" ::: "memory");

        f32x4 acc[2] = {};
        #pragma unroll
        for (int kc = 0; kc < 6; kc++)
            #pragma unroll
            for (int ct = 0; ct < 2; ct++) {
                int r1 = ct * 16 + c;
                const bf16_t* pp = wbuf[p] + r1 * 192 + ((kc * 32 + 8 * g) ^ ((r1 & 7) << 3));
                short8 b = *(const short8*)pp;
                acc[ct] = __builtin_amdgcn_mfma_f32_16x16x32_bf16(a[kc], b, acc[ct], 0, 0, 0);
            }

        const int bsel = nc / 6, h = nc - bsel * 6;
        #pragma unroll
        for (int ct = 0; ct < 2; ct++) {
            float bv = sbias[nc * 32 + ct * 16 + c];
            #pragma unroll
            for (int r = 0; r < 4; r++) {
                float val = acc[ct][r] + bv;
                if (bsel == 0)
                    qo[rb4[r] + h * 294912 + ct * 16 + c] = f2b(val * QSCALE);
                else if (bsel == 1)
                    ko[kb4[r] + h * 393216 + ct * 16 + c] = f2b(val);
                else
                    vo[rb4[r] + h * 294912 + ct * 16 + c] = f2b(val);
            }
        }

        asm volatile("" ::: "memory");
        __builtin_amdgcn_s_barrier();   // wbuf[p] consumed before nc+2 DMA
        asm volatile("" ::: "memory");
    }
}

// ---------------------------------------------------------------------------
// Attention v3: K tile + bias row via async DMA. (r23 proven)
// ---------------------------------------------------------------------------
__global__ __launch_bounds__(576, 6) void attn_kernel(
    const bf16_t* __restrict__ qb, const bf16_t* __restrict__ kg,
    const bf16_t* __restrict__ vb, const float* __restrict__ btT,
    bf16_t* __restrict__ ob)
{
    __shared__ bf16_t klds[6144];               // [144][40] padded, DMA'd
    __shared__ bf16_t vT[32 * 168];             // [d][kv], kv 144..159 zero
    __shared__ float biaslds[3584];             // DMA'd from padded btT row
    __shared__ int eqa[144], ema[144], cnta[144];
    __shared__ bf16_t pscratch[9 * 640];        // per-wave 16 x 40

    const int t   = threadIdx.x;
    const int bid = blockIdx.x;              // ((bl*6 + h)*64 + w)
    const int wi  = bid & 63;
    const int bh  = bid >> 6;
    const int h   = bh % 6;
    const int bl  = bh / 6;
    const int tb  = bid * 4608;
    const int wh  = wi * 6 + h;

    const int s = t / 64;        // wave = strip (0..8)
    const int l = t & 63;
    const int c = l & 15, g = l >> 4;

    // ---- issue K + bias DMA first; everything below hides their latency ----
    for (int sg = s; sg < 12; sg += 9)          // 12 KB K tile
        gload_lds16(kg + bid * 6144 + sg * 512 + l * 8, klds + sg * 512 + l * 8);
    for (int sg = s; sg < 14; sg += 9)          // 14 KB bias row (fp32)
        gload_lds16((const bf16_t*)(btT + wh * 3584) + sg * 512 + l * 8,
                    (bf16_t*)biaslds + sg * 512 + l * 8);

    // ---- V transpose staging (register path) ----
    for (int idx = t; idx < 1152; idx += 576) {
        int r = idx >> 3, q4 = (idx & 7) * 4;
        ushort4 vv = *(const ushort4*)(vb + tb + r * 32 + q4);
        vT[(q4 + 0) * 168 + r] = vv.x;
        vT[(q4 + 1) * 168 + r] = vv.y;
        vT[(q4 + 2) * 168 + r] = vv.z;
        vT[(q4 + 3) * 168 + r] = vv.w;
    }
    if (t < 512) vT[(t >> 4) * 168 + 144 + (t & 15)] = 0;   // zero pad rows
    if (t < 144) {
        int n = t;
        int w0 = n / 72; int rn = n - w0 * 72;
        int w1 = rn / 12; int w2 = rn - w1 * 12;
        eqa[t] = 828 * w0 + 23 * w1 + w2;
        ema[t] = 1656 * w0 + 138 * w1 + 12 * w2 + 11;
        int npl = wi >> 4, nlat = wi & 15;
        int p0 = npl * 2 + w0, p1 = nlat * 6 + w1, p2 = bl * 12 + w2;
        int sa = (p0 < 6) ? 0 : ((p0 < 7) ? 1 : 2);
        int sb = (p1 < 90) ? 0 : ((p1 < 93) ? 1 : 2);
        int sc = (p2 < 174) ? 0 : 1;
        cnta[t] = sa * 9 + sb * 3 + sc;
    }

    // Q A-frag straight from global (row 16s+c of this tile)
    short8 aq = *(const short8*)(qb + tb + (16 * s + c) * 32 + 8 * g);
    __syncthreads();   // drains vmcnt(0)+lgkmcnt(0): DMA + all staging visible

    // ---- QK^T ----
    f32x4 acc[9];
    #pragma unroll
    for (int kt = 0; kt < 9; kt++) {
        short8 bk = *(const short8*)(klds + (16 * kt + c) * 40 + 8 * g);
        f32x4 z = {0.f, 0.f, 0.f, 0.f};
        acc[kt] = __builtin_amdgcn_mfma_f32_16x16x32_bf16(aq, bk, z, 0, 0, 0);
    }

    // ---- bias + mask ----
    int eqr[4], cnr[4];
    #pragma unroll
    for (int r = 0; r < 4; r++) {
        int R = 16 * s + 4 * g + r;
        eqr[r] = eqa[R]; cnr[r] = cnta[R];
    }
    #pragma unroll
    for (int kt = 0; kt < 9; kt++) {
        int emc = ema[16 * kt + c], cnc = cnta[16 * kt + c];
        #pragma unroll
        for (int r = 0; r < 4; r++)
            acc[kt][r] += biaslds[eqr[r] + emc] + ((cnr[r] == cnc) ? 0.f : -100.f);
    }

    // ---- softmax over 144 cols ----
    float mx[4] = {-1e30f, -1e30f, -1e30f, -1e30f};
    #pragma unroll
    for (int kt = 0; kt < 9; kt++)
        #pragma unroll
        for (int r = 0; r < 4; r++) mx[r] = fmaxf(mx[r], acc[kt][r]);
    #pragma unroll
    for (int r = 0; r < 4; r++) {
        mx[r] = fmaxf(mx[r], __shfl_xor(mx[r], 1));
        mx[r] = fmaxf(mx[r], __shfl_xor(mx[r], 2));
        mx[r] = fmaxf(mx[r], __shfl_xor(mx[r], 4));
        mx[r] = fmaxf(mx[r], __shfl_xor(mx[r], 8));
    }
    float sm[4] = {0.f, 0.f, 0.f, 0.f};
    #pragma unroll
    for (int kt = 0; kt < 9; kt++)
        #pragma unroll
        for (int r = 0; r < 4; r++) {
            float e = __expf(acc[kt][r] - mx[r]);
            acc[kt][r] = e; sm[r] += e;
        }
    #pragma unroll
    for (int r = 0; r < 4; r++) {
        sm[r] += __shfl_xor(sm[r], 1);
        sm[r] += __shfl_xor(sm[r], 2);
        sm[r] += __shfl_xor(sm[r], 4);
        sm[r] += __shfl_xor(sm[r], 8);
        sm[r] = 1.0f / sm[r];
    }

    // ---- PV : O[16 x 32] per wave, K padded to 160; B-frags from vT ----
    bf16_t* ps = pscratch + s * 640;
    f32x4 oacc[2] = {{0.f,0.f,0.f,0.f}, {0.f,0.f,0.f,0.f}};
    for (int kc = 0; kc < 5; kc++) {
        #pragma unroll
        for (int tt = 0; tt < 2; tt++) {
            int kt = 2 * kc + tt;
            #pragma unroll
            for (int r = 0; r < 4; r++) {
                float pv = (kt < 9) ? acc[kt][r] * sm[r] : 0.f;
                ps[(4 * g + r) * 40 + tt * 16 + c] = f2b(pv);
            }
        }
        short8 ap = *(const short8*)(ps + c * 40 + 8 * g);
        #pragma unroll
        for (int dt = 0; dt < 2; dt++) {
            short8 bv = *(const short8*)(vT + (dt * 16 + c) * 168 + kc * 32 + 8 * g);
            oacc[dt] = __builtin_amdgcn_mfma_f32_16x16x32_bf16(ap, bv, oacc[dt], 0, 0, 0);
        }
    }
    #pragma unroll
    for (int dt = 0; dt < 2; dt++)
        #pragma unroll
        for (int r = 0; r < 4; r++)
            ob[tb + (16 * s + 4 * g + r) * 32 + dt * 16 + c] = f2b(oacc[dt][r]);
}

// ---------------------------------------------------------------------------
// Proj v2: A-frags direct from global o; W via DMA ping-pong. (r20 proven)
// ---------------------------------------------------------------------------
__global__ __launch_bounds__(256, 4) void proj_mfma_kernel(
    const bf16_t* __restrict__ ot, const float* __restrict__ x,
    const bf16_t* __restrict__ wp,  // [6 chunks][6144] swizzled
    const float* __restrict__ pb,
    float* __restrict__ xa)
{
    __shared__ bf16_t wbuf[2][6144];
    __shared__ float sbias[192];

    const int t = threadIdx.x, m0 = blockIdx.x * 64;
    const int l = t & 63, wv = t >> 6;
    const int c = l & 15, g = l >> 4;
    const int soff = wv * 512 + l * 8;

    #pragma unroll
    for (int i = 0; i < 3; i++)
        gload_lds16(wp + i * 2048 + soff, wbuf[0] + i * 2048 + soff);

    for (int v = t; v < 192; v += 256) sbias[v] = pb[v];

    // A-frags straight from global o (row c of wave's strip)
    const int ob_ = tiled_base(m0 + 16 * wv + c);
    short8 a[6];
    #pragma unroll
    for (int kc = 0; kc < 6; kc++)
        a[kc] = *(const short8*)(ot + ob_ + kc * 294912 + 8 * g);

    int xoff[4];
    #pragma unroll
    for (int r = 0; r < 4; r++) xoff[r] = src_off(m0 + 16 * wv + 4 * g + r);
    __syncthreads();                     // sbias staged

    for (int nc = 0; nc < 6; nc++) {
        const int p = nc & 1;
        if (nc < 5) {
            #pragma unroll
            for (int i = 0; i < 3; i++)
                gload_lds16(wp + (nc + 1) * 6144 + i * 2048 + soff,
                            wbuf[p ^ 1] + i * 2048 + soff);
            asm volatile("s_waitcnt vmcnt(3)");   // drain chunk nc (+older ops)
        } else {
            asm volatile("s_waitcnt vmcnt(0)");
        }
        asm volatile("" ::: "memory");
        __builtin_amdgcn_s_barrier();
        asm volatile("" ::: "memory");

        f32x4 acc[2] = {};
        #pragma unroll
        for (int kc = 0; kc < 6; kc++)
            #pragma unroll
            for (int ct = 0; ct < 2; ct++) {
                int r1 = ct * 16 + c;
                const bf16_t* pp = wbuf[p] + r1 * 192 + ((kc * 32 + 8 * g) ^ ((r1 & 7) << 3));
                short8 b = *(const short8*)pp;
                acc[ct] = __builtin_amdgcn_mfma_f32_16x16x32_bf16(a[kc], b, acc[ct], 0, 0, 0);
            }

        #pragma unroll
        for (int ct = 0; ct < 2; ct++) {
            int col = nc * 32 + ct * 16 + c;
            float bv = sbias[col];
            #pragma unroll
            for (int r = 0; r < 4; r++) {
                int off = xoff[r] + col;
                xa[off] = acc[ct][r] + bv + x[off];
            }
        }

        asm volatile("" ::: "memory");
        __builtin_amdgcn_s_barrier();   // wbuf[p] consumed before nc+2 DMA
        asm volatile("" ::: "memory");
    }
}

// ---------------------------------------------------------------------------
// Fused MLP v10: v8b + W2 double-buffer. Per nc: ONE vmcnt + 3 barriers
// (was 2 + 4); W2 chunk gets a full iteration of prefetch lead; FC2 needs
// no wait (its chunk drained at loop top). LDS 36.9 KB.
// ---------------------------------------------------------------------------
__global__ __launch_bounds__(256, 4) void mlp_kernel(
    const float* __restrict__ xa,
    const float* __restrict__ ln2w, const float* __restrict__ ln2b,
    const bf16_t* __restrict__ w1s,    // [24 chunks][6144] swizzled
    const float* __restrict__ b1,
    const bf16_t* __restrict__ w2s,    // [24 chunks][6144] permuted
    const float* __restrict__ b2,
    float* __restrict__ out)
{
    __shared__ bf16_t buf1[6144];       // W1 chunk: [32 fcol][192 k] (swizzled)
    __shared__ bf16_t buf2[2][6144];    // W2 chunks: [192 col][32 kl] (permuted)

    const int t = threadIdx.x, m0 = blockIdx.x * 64;
    const int l = t & 63, wv = t >> 6;
    const int c = l & 15, g = l >> 4;
    const int soff = wv * 512 + l * 8;   // DMA elem offset within 2048-seg

    // prologue: issue W1 chunk 0 AND W2 chunk 0; LN2 hides their latency
    #pragma unroll
    for (int i = 0; i < 3; i++) {
        gload_lds16(w1s + i * 2048 + soff, buf1 + i * 2048 + soff);
        gload_lds16(w2s + i * 2048 + soff, buf2[0] + i * 2048 + soff);
    }

    // ---- LN2 on this lane's token, result held as FC1 B-frags in regs ----
    const float* xr = xa + (m0 + 16 * wv + c) * 192;
    float fa[6][8];
    float ss = 0.f, s2 = 0.f;
    #pragma unroll
    for (int kc = 0; kc < 6; kc++) {
        float4 v0 = *(const float4*)(xr + kc * 32 + 8 * g);
        float4 v1 = *(const float4*)(xr + kc * 32 + 8 * g + 4);
        fa[kc][0]=v0.x; fa[kc][1]=v0.y; fa[kc][2]=v0.z; fa[kc][3]=v0.w;
        fa[kc][4]=v1.x; fa[kc][5]=v1.y; fa[kc][6]=v1.z; fa[kc][7]=v1.w;
        ss += v0.x+v0.y+v0.z+v0.w + v1.x+v1.y+v1.z+v1.w;
        s2 += v0.x*v0.x+v0.y*v0.y+v0.z*v0.z+v0.w*v0.w
            + v1.x*v1.x+v1.y*v1.y+v1.z*v1.z+v1.w*v1.w;
    }
    ss += __shfl_xor(ss, 16); s2 += __shfl_xor(s2, 16);
    ss += __shfl_xor(ss, 32); s2 += __shfl_xor(s2, 32);
    float mu = ss * (1.f / 192.f);
    float rs = 1.0f / sqrtf(s2 * (1.f / 192.f) - mu * mu + 1e-5f);

    short8 xb[6];
    #pragma unroll
    for (int kc = 0; kc < 6; kc++) {
        float4 gw0 = *(const float4*)(ln2w + kc * 32 + 8 * g);
        float4 gw1 = *(const float4*)(ln2w + kc * 32 + 8 * g + 4);
        float4 gb0 = *(const float4*)(ln2b + kc * 32 + 8 * g);
        float4 gb1 = *(const float4*)(ln2b + kc * 32 + 8 * g + 4);
        union { bf16_t e[8]; short8 v; } u;
        u.e[0] = f2b((fa[kc][0]-mu)*rs*gw0.x + gb0.x);
        u.e[1] = f2b((fa[kc][1]-mu)*rs*gw0.y + gb0.y);
        u.e[2] = f2b((fa[kc][2]-mu)*rs*gw0.z + gb0.z);
        u.e[3] = f2b((fa[kc][3]-mu)*rs*gw0.w + gb0.w);
        u.e[4] = f2b((fa[kc][4]-mu)*rs*gw1.x + gb1.x);
        u.e[5] = f2b((fa[kc][5]-mu)*rs*gw1.y + gb1.y);
        u.e[6] = f2b((fa[kc][6]-mu)*rs*gw1.z + gb1.z);
        u.e[7] = f2b((fa[kc][7]-mu)*rs*gw1.w + gb1.w);
        xb[kc] = u.v;
    }

    f32x4 acc2[12] = {};

    for (int nc = 0; nc < 24; nc++) {
        const int p2 = nc & 1;              // buf2 slot holding chunk nc
        // bias loads FIRST (oldest in queue -> drained by the counted wait)
        float4 bvv[2];
        #pragma unroll
        for (int ctA = 0; ctA < 2; ctA++)
            bvv[ctA] = *(const float4*)(b1 + nc * 32 + ctA * 16 + 4 * g);

        // issue W2 chunk nc+1 -> other buf2 slot (full iteration of lead)
        if (nc < 23) {
            #pragma unroll
            for (int i = 0; i < 3; i++)
                gload_lds16(w2s + (nc + 1) * 6144 + i * 2048 + soff,
                            buf2[p2 ^ 1] + i * 2048 + soff);
            // steady state queue: W2(nc)[3] W1(nc)[3] bias[2] W2(nc+1)[3] = 11
            asm volatile("s_waitcnt vmcnt(3)");  // drain W2(nc)+W1(nc)+bias
        } else {
            asm volatile("s_waitcnt vmcnt(0)");
        }
        asm volatile("" ::: "memory");
        __builtin_amdgcn_s_barrier();            // chunk nc visible to all
        asm volatile("" ::: "memory");

        // ---- FC1 swapped: D[fcol-local][token], A from swizzled buf1 ----
        f32x4 acc1[2] = {};
        #pragma unroll
        for (int kc = 0; kc < 6; kc++)
            #pragma unroll
            for (int ctA = 0; ctA < 2; ctA++) {
                int r1 = ctA * 16 + c;
                const bf16_t* p = buf1 + r1 * 192 + ((kc * 32 + 8 * g) ^ ((r1 & 7) << 3));
                short8 aw = *(const short8*)p;
                acc1[ctA] = __builtin_amdgcn_mfma_f32_16x16x32_bf16(aw, xb[kc], acc1[ctA], 0, 0, 0);
            }

        // ---- bias + fast GELU -> FC2 A-frags in regs ----
        short4v a2[2];
        #pragma unroll
        for (int ctA = 0; ctA < 2; ctA++) {
            union { bf16_t e[4]; short4v v; } u;
            u.e[0] = f2b(gelu_fast(acc1[ctA][0] + bvv[ctA].x));
            u.e[1] = f2b(gelu_fast(acc1[ctA][1] + bvv[ctA].y));
            u.e[2] = f2b(gelu_fast(acc1[ctA][2] + bvv[ctA].z));
            u.e[3] = f2b(gelu_fast(acc1[ctA][3] + bvv[ctA].w));
            a2[ctA] = u.v;
        }

        asm volatile("" ::: "memory");
        __builtin_amdgcn_s_barrier();           // all waves done reading buf1
        asm volatile("" ::: "memory");

        // issue W1 chunk nc+1 -> buf1 (lands before next iter's counted wait)
        if (nc < 23) {
            #pragma unroll
            for (int i = 0; i < 3; i++)
                gload_lds16(w1s + (nc + 1) * 6144 + i * 2048 + soff,
                            buf1 + i * 2048 + soff);
        }

        // ---- FC2 partial from buf2[p2] (already drained; NO wait) ----
        #pragma unroll
        for (int ctB = 0; ctB < 12; ctB++) {
            const bf16_t* p = buf2[p2] + (ctB * 16 + c) * 32 + g * 8;
            union { short4v h[2]; short8 v; } bb;
            bb.v = *(const short8*)p;
            acc2[ctB] = MFMA16(a2[0], bb.h[0], acc2[ctB]);
            acc2[ctB] = MFMA16(a2[1], bb.h[1], acc2[ctB]);
        }

        asm volatile("" ::: "memory");
        __builtin_amdgcn_s_barrier();   // buf2[p2] consumed before nc+1 top DMA
        asm volatile("" ::: "memory");
    }

    // ---- epilogue: out += fc2 + bias (out holds xa) ----
    #pragma unroll
    for (int ctB = 0; ctB < 12; ctB++) {
        int col = ctB * 16 + c;
        float bv = b2[col];
        #pragma unroll
        for (int r = 0; r < 4; r++) {
            int off = (m0 + 16 * wv + 4 * g + r) * 192 + col;
            out[off] = acc2[ctB][r] + bv + out[off];
        }
    }
}

// ---------------------------------------------------------------------------
extern "C" void kernel_launch(void* const* d_in, const int* in_sizes, int n_in,
                              void* d_out, int out_size, void* d_ws, size_t ws_size,
                              hipStream_t stream)
{
    const float* x      = (const float*)d_in[0];
    const float* ln1w   = (const float*)d_in[1];
    const float* ln1b   = (const float*)d_in[2];
    const float* qkvw   = (const float*)d_in[3];
    const float* qkvb   = (const float*)d_in[4];
    const float* projw  = (const float*)d_in[5];
    const float* projb  = (const float*)d_in[6];
    const float* biast  = (const float*)d_in[7];
    const float* ln2w   = (const float*)d_in[8];
    const float* ln2b   = (const float*)d_in[9];
    const float* fc1w   = (const float*)d_in[10];
    const float* fc1b   = (const float*)d_in[11];
    const float* fc2w   = (const float*)d_in[12];
    const float* fc2b   = (const float*)d_in[13];
    float* out = (float*)d_out;

    // ws layout (bytes): q 53.1MB | K-padded 70.8MB | v 53.1MB | weights | btT
    const size_t SLOTB = 53084160;      // 138240*192 bf16 bytes
    const size_t KSLOT = 70778880;      // 5760*6144 bf16 bytes (padded K)
    char* base = (char*)d_ws;
    bf16_t* qbuf = (bf16_t*)(base);
    bf16_t* kbuf = (bf16_t*)(base + SLOTB);
    bf16_t* vbuf = (bf16_t*)(base + SLOTB + KSLOT);
    bf16_t* wq   = (bf16_t*)(base + 2 * SLOTB + KSLOT);   // [18][6144]
    bf16_t* wpp  = wq   + 110592;                         // [6][6144]
    bf16_t* w1s  = wpp  + 36864;                          // [24][6144]
    bf16_t* w2s  = w1s  + 147456;                         // [24][6144]
    float*  btT  = (float*)(w2s + 147456);                // [384][3584] padded

    prep_kernel<<<7104, 256, 0, stream>>>(qkvw, projw, fc1w, fc2w, biast,
                                          wq, wpp, w1s, w2s, btT);

    qkv_mfma_kernel<<<2160, 256, 0, stream>>>(x, ln1w, ln1b, wq, qkvb, qbuf, kbuf, vbuf);
    attn_kernel<<<5760, 576, 0, stream>>>(qbuf, kbuf, vbuf, btT, qbuf);
    proj_mfma_kernel<<<2160, 256, 0, stream>>>(qbuf, x, wpp, projb, out);
    mlp_kernel<<<2160, 256, 0, stream>>>(out, ln2w, ln2b, w1s, fc1b, w2s, fc2b, out);
}

// Round 25
// 416.330 us; speedup vs baseline: 1.0390x; 1.0390x over previous
//
#include <hip/hip_runtime.h>
#include <math.h>

#define DI __device__ __forceinline__

// PL=8 LAT=96 LON=180 C=192 H=6 D=32 ; windows (2,6,12) shift (1,3,6)
// NPL=4 NLAT=16 NLON=15 NW=64 N=144 L=138240 ; BIAS_SIZE=3444
constexpr float QSCALE = 0.17677669529663687f; // 32^-0.5

typedef unsigned short bf16_t;
typedef __attribute__((ext_vector_type(8))) short short8;
typedef __attribute__((ext_vector_type(4))) short short4v;
typedef __attribute__((ext_vector_type(4))) float f32x4;

#if __has_builtin(__builtin_amdgcn_mfma_f32_16x16x16_bf16)
DI f32x4 MFMA16(short4v a, short4v b, f32x4 c) {
    return __builtin_amdgcn_mfma_f32_16x16x16_bf16(a, b, c, 0, 0, 0);
}
#elif __has_builtin(__builtin_amdgcn_mfma_f32_16x16x16bf16_1k)
DI f32x4 MFMA16(short4v a, short4v b, f32x4 c) {
    return __builtin_amdgcn_mfma_f32_16x16x16bf16_1k(a, b, c, 0, 0, 0);
}
#else
DI f32x4 MFMA16(short4v a, short4v b, f32x4 c) {
    asm volatile("v_mfma_f32_16x16x16_bf16 %0, %1, %2, %0"
                 : "+v"(c) : "v"(a), "v"(b));
    return c;
}
#endif

DI unsigned short f2b(float f) {            // fp32 -> bf16 bits, RNE
    unsigned u = __builtin_bit_cast(unsigned, f);
    return (unsigned short)((u + 0x7FFFu + ((u >> 16) & 1u)) >> 16);
}

// async global->LDS DMA, 16 B per lane, linear dest (wave base + lane*16)
DI void gload_lds16(const bf16_t* g, bf16_t* l) {
    __builtin_amdgcn_global_load_lds(
        (const __attribute__((address_space(1))) unsigned int*)(const void*)g,
        (__attribute__((address_space(3))) unsigned int*)(void*)l, 16, 0, 0);
}

// windowed row -> original token offset (*192), applying forward roll (-1,-3,-6)
DI int src_off(int row) {
    int bl  = row / 9216;  int rem = row - bl * 9216;   // 9216 = 64*144
    int wi  = rem / 144;   int n   = rem - wi * 144;
    int npl = wi >> 4,     nlat = wi & 15;
    int w0  = n / 72;      int rn = n - w0 * 72;
    int w1  = rn / 12;     int w2 = rn - w1 * 12;
    int pl = npl * 2 + w0 + 1;  if (pl >= 8)   pl -= 8;
    int la = nlat * 6 + w1 + 3; if (la >= 96)  la -= 96;
    int lo = bl * 12 + w2 + 6;  if (lo >= 180) lo -= 180;
    return ((pl * 96 + la) * 180 + lo) * 192;
}

DI int tiled_base(int row) {   // windowed row -> q/v tiled base (h,d added later)
    int bl = row / 9216; int rem = row - bl * 9216;
    int wi = rem / 144;  int n = rem - wi * 144;
    return bl * 1769472 + wi * 4608 + n * 32;
}

DI int k40_base(int row) {     // windowed row -> padded K tile base (stride 40)
    int bl = row / 9216; int rem = row - bl * 9216;
    int wi = rem / 144;  int n = rem - wi * 144;
    return bl * 2359296 + wi * 6144 + n * 40;   // bid*6144 + n*40 (h added later)
}

// fast GELU: x*sigmoid(1.595769x + 0.0713548x^3); |err| vs exact < ~1e-3
DI float gelu_fast(float x) {
    float t  = x * x;
    float in = __builtin_fmaf(t, 0.07135481283f, 1.5957691216f);
    float e  = __expf(-x * in);
    return x * __builtin_amdgcn_rcpf(1.0f + e);
}

// ---------------------------------------------------------------------------
// Fused prep: all weight conversions + bias transpose (padded 3584) in ONE.
// Ranges: wq 110592 | wpp 36864 | w1s 147456 | w2s 147456 | btT 1376256
// ---------------------------------------------------------------------------
__global__ __launch_bounds__(256) void prep_kernel(
    const float* __restrict__ qkvw, const float* __restrict__ projw,
    const float* __restrict__ fc1w, const float* __restrict__ fc2w,
    const float* __restrict__ biast,
    bf16_t* __restrict__ wq, bf16_t* __restrict__ wpp,
    bf16_t* __restrict__ w1s, bf16_t* __restrict__ w2s,
    float* __restrict__ btT)
{
    int i = blockIdx.x * 256 + threadIdx.x;
    if (i < 110592) {                       // qkv W: 18 chunks of 32 cols
        int fcol = i / 192, k = i - fcol * 192;
        int nc = fcol >> 5, row = fcol & 31;
        wq[nc * 6144 + row * 192 + (k ^ ((row & 7) << 3))] = f2b(qkvw[k * 576 + fcol]);
        return;
    }
    i -= 110592;
    if (i < 36864) {                        // proj W: 6 chunks
        int fcol = i / 192, k = i - fcol * 192;
        int nc = fcol >> 5, row = fcol & 31;
        wpp[nc * 6144 + row * 192 + (k ^ ((row & 7) << 3))] = f2b(projw[k * 192 + fcol]);
        return;
    }
    i -= 36864;
    if (i < 147456) {                       // fc1 W: 24 chunks
        int fcol = i / 192, k = i - fcol * 192;
        int nc = fcol >> 5, row = fcol & 31;
        w1s[nc * 6144 + row * 192 + (k ^ ((row & 7) << 3))] = f2b(fc1w[k * 768 + fcol]);
        return;
    }
    i -= 147456;
    if (i < 147456) {                       // fc2 W: 24 chunks, [g][ctA][r] perm
        int k = i / 192, col = i - k * 192;
        int nc = k >> 5, kl = k & 31;
        int ctA = kl >> 4, g = (kl >> 2) & 3, r = kl & 3;
        w2s[nc * 6144 + col * 32 + g * 8 + ctA * 4 + r] = f2b(fc2w[i]);
        return;
    }
    i -= 147456;
    if (i < 1376256) {                      // bias transpose, padded stride 3584
        int wh = i / 3584, e = i - wh * 3584;
        btT[i] = (e < 3444) ? biast[e * 384 + wh] : 0.0f;
    }
}

// ---------------------------------------------------------------------------
// QKV v3b: LN1 fused, A in regs; W chunks via DMA ping-pong. K output goes
// to padded per-window tiles (stride 40) so attn can DMA it linearly.
// ---------------------------------------------------------------------------
__global__ __launch_bounds__(256, 4) void qkv_mfma_kernel(
    const float* __restrict__ x,
    const float* __restrict__ ln1w, const float* __restrict__ ln1b,
    const bf16_t* __restrict__ wq,   // [18 chunks][6144] swizzled
    const float* __restrict__ bias,  // [576]
    bf16_t* __restrict__ qo, bf16_t* __restrict__ ko, bf16_t* __restrict__ vo)
{
    __shared__ bf16_t wbuf[2][6144];
    __shared__ float lw[192], lb[192], sbias[576];

    const int t  = threadIdx.x;
    const int m0 = blockIdx.x * 64;
    const int l = t & 63, wv = t >> 6;
    const int c = l & 15, g = l >> 4;
    const int soff = wv * 512 + l * 8;

    #pragma unroll
    for (int i = 0; i < 3; i++)
        gload_lds16(wq + i * 2048 + soff, wbuf[0] + i * 2048 + soff);

    for (int v = t; v < 192; v += 256) { lw[v] = ln1w[v]; lb[v] = ln1b[v]; }
    for (int v = t; v < 576; v += 256) sbias[v] = bias[v];

    const int msrc = src_off(m0 + 16 * wv + c);

    float fa[6][8];
    float ss = 0.f, s2 = 0.f;
    #pragma unroll
    for (int kc = 0; kc < 6; kc++) {
        float4 v0 = *(const float4*)(x + msrc + kc * 32 + 8 * g);
        float4 v1 = *(const float4*)(x + msrc + kc * 32 + 8 * g + 4);
        fa[kc][0]=v0.x; fa[kc][1]=v0.y; fa[kc][2]=v0.z; fa[kc][3]=v0.w;
        fa[kc][4]=v1.x; fa[kc][5]=v1.y; fa[kc][6]=v1.z; fa[kc][7]=v1.w;
        ss += v0.x+v0.y+v0.z+v0.w + v1.x+v1.y+v1.z+v1.w;
        s2 += v0.x*v0.x+v0.y*v0.y+v0.z*v0.z+v0.w*v0.w
            + v1.x*v1.x+v1.y*v1.y+v1.z*v1.z+v1.w*v1.w;
    }
    ss += __shfl_xor(ss, 16); s2 += __shfl_xor(s2, 16);
    ss += __shfl_xor(ss, 32); s2 += __shfl_xor(s2, 32);
    float mu = ss * (1.f / 192.f);
    float rs = 1.0f / sqrtf(s2 * (1.f / 192.f) - mu * mu + 1e-5f);
    __syncthreads();                        // lw/lb staged

    short8 a[6];
    #pragma unroll
    for (int kc = 0; kc < 6; kc++) {
        union { bf16_t e[8]; short8 v; } u;
        #pragma unroll
        for (int j = 0; j < 8; j++) {
            int col = kc * 32 + 8 * g + j;
            u.e[j] = f2b((fa[kc][j] - mu) * rs * lw[col] + lb[col]);
        }
        a[kc] = u.v;
    }

    int rb4[4], kb4[4];
    #pragma unroll
    for (int r = 0; r < 4; r++) {
        int row = m0 + 16 * wv + 4 * g + r;
        rb4[r] = tiled_base(row);
        kb4[r] = k40_base(row);
    }

    for (int nc = 0; nc < 18; nc++) {
        const int p = nc & 1;
        if (nc < 17) {
            #pragma unroll
            for (int i = 0; i < 3; i++)
                gload_lds16(wq + (nc + 1) * 6144 + i * 2048 + soff,
                            wbuf[p ^ 1] + i * 2048 + soff);
            asm volatile("s_waitcnt vmcnt(3)");   // drain chunk nc (+older ops)
        } else {
            asm volatile("s_waitcnt vmcnt(0)");
        }
        asm volatile("" ::: "memory");
        __builtin_amdgcn_s_barrier();
        asm volatile("" ::: "memory");

        f32x4 acc[2] = {};
        #pragma unroll
        for (int kc = 0; kc < 6; kc++)
            #pragma unroll
            for (int ct = 0; ct < 2; ct++) {
                int r1 = ct * 16 + c;
                const bf16_t* pp = wbuf[p] + r1 * 192 + ((kc * 32 + 8 * g) ^ ((r1 & 7) << 3));
                short8 b = *(const short8*)pp;
                acc[ct] = __builtin_amdgcn_mfma_f32_16x16x32_bf16(a[kc], b, acc[ct], 0, 0, 0);
            }

        const int bsel = nc / 6, h = nc - bsel * 6;
        #pragma unroll
        for (int ct = 0; ct < 2; ct++) {
            float bv = sbias[nc * 32 + ct * 16 + c];
            #pragma unroll
            for (int r = 0; r < 4; r++) {
                float val = acc[ct][r] + bv;
                if (bsel == 0)
                    qo[rb4[r] + h * 294912 + ct * 16 + c] = f2b(val * QSCALE);
                else if (bsel == 1)
                    ko[kb4[r] + h * 393216 + ct * 16 + c] = f2b(val);
                else
                    vo[rb4[r] + h * 294912 + ct * 16 + c] = f2b(val);
            }
        }

        asm volatile("" ::: "memory");
        __builtin_amdgcn_s_barrier();   // wbuf[p] consumed before nc+2 DMA
        asm volatile("" ::: "memory");
    }
}

// ---------------------------------------------------------------------------
// Attention v3: K tile + bias row via async DMA. (r23 proven)
// ---------------------------------------------------------------------------
__global__ __launch_bounds__(576, 6) void attn_kernel(
    const bf16_t* __restrict__ qb, const bf16_t* __restrict__ kg,
    const bf16_t* __restrict__ vb, const float* __restrict__ btT,
    bf16_t* __restrict__ ob)
{
    __shared__ bf16_t klds[6144];               // [144][40] padded, DMA'd
    __shared__ bf16_t vT[32 * 168];             // [d][kv], kv 144..159 zero
    __shared__ float biaslds[3584];             // DMA'd from padded btT row
    __shared__ int eqa[144], ema[144], cnta[144];
    __shared__ bf16_t pscratch[9 * 640];        // per-wave 16 x 40

    const int t   = threadIdx.x;
    const int bid = blockIdx.x;              // ((bl*6 + h)*64 + w)
    const int wi  = bid & 63;
    const int bh  = bid >> 6;
    const int h   = bh % 6;
    const int bl  = bh / 6;
    const int tb  = bid * 4608;
    const int wh  = wi * 6 + h;

    const int s = t / 64;        // wave = strip (0..8)
    const int l = t & 63;
    const int c = l & 15, g = l >> 4;

    // ---- issue K + bias DMA first; everything below hides their latency ----
    for (int sg = s; sg < 12; sg += 9)          // 12 KB K tile
        gload_lds16(kg + bid * 6144 + sg * 512 + l * 8, klds + sg * 512 + l * 8);
    for (int sg = s; sg < 14; sg += 9)          // 14 KB bias row (fp32)
        gload_lds16((const bf16_t*)(btT + wh * 3584) + sg * 512 + l * 8,
                    (bf16_t*)biaslds + sg * 512 + l * 8);

    // ---- V transpose staging (register path) ----
    for (int idx = t; idx < 1152; idx += 576) {
        int r = idx >> 3, q4 = (idx & 7) * 4;
        ushort4 vv = *(const ushort4*)(vb + tb + r * 32 + q4);
        vT[(q4 + 0) * 168 + r] = vv.x;
        vT[(q4 + 1) * 168 + r] = vv.y;
        vT[(q4 + 2) * 168 + r] = vv.z;
        vT[(q4 + 3) * 168 + r] = vv.w;
    }
    if (t < 512) vT[(t >> 4) * 168 + 144 + (t & 15)] = 0;   // zero pad rows
    if (t < 144) {
        int n = t;
        int w0 = n / 72; int rn = n - w0 * 72;
        int w1 = rn / 12; int w2 = rn - w1 * 12;
        eqa[t] = 828 * w0 + 23 * w1 + w2;
        ema[t] = 1656 * w0 + 138 * w1 + 12 * w2 + 11;
        int npl = wi >> 4, nlat = wi & 15;
        int p0 = npl * 2 + w0, p1 = nlat * 6 + w1, p2 = bl * 12 + w2;
        int sa = (p0 < 6) ? 0 : ((p0 < 7) ? 1 : 2);
        int sb = (p1 < 90) ? 0 : ((p1 < 93) ? 1 : 2);
        int sc = (p2 < 174) ? 0 : 1;
        cnta[t] = sa * 9 + sb * 3 + sc;
    }

    // Q A-frag straight from global (row 16s+c of this tile)
    short8 aq = *(const short8*)(qb + tb + (16 * s + c) * 32 + 8 * g);
    __syncthreads();   // drains vmcnt(0)+lgkmcnt(0): DMA + all staging visible

    // ---- QK^T ----
    f32x4 acc[9];
    #pragma unroll
    for (int kt = 0; kt < 9; kt++) {
        short8 bk = *(const short8*)(klds + (16 * kt + c) * 40 + 8 * g);
        f32x4 z = {0.f, 0.f, 0.f, 0.f};
        acc[kt] = __builtin_amdgcn_mfma_f32_16x16x32_bf16(aq, bk, z, 0, 0, 0);
    }

    // ---- bias + mask ----
    int eqr[4], cnr[4];
    #pragma unroll
    for (int r = 0; r < 4; r++) {
        int R = 16 * s + 4 * g + r;
        eqr[r] = eqa[R]; cnr[r] = cnta[R];
    }
    #pragma unroll
    for (int kt = 0; kt < 9; kt++) {
        int emc = ema[16 * kt + c], cnc = cnta[16 * kt + c];
        #pragma unroll
        for (int r = 0; r < 4; r++)
            acc[kt][r] += biaslds[eqr[r] + emc] + ((cnr[r] == cnc) ? 0.f : -100.f);
    }

    // ---- softmax over 144 cols ----
    float mx[4] = {-1e30f, -1e30f, -1e30f, -1e30f};
    #pragma unroll
    for (int kt = 0; kt < 9; kt++)
        #pragma unroll
        for (int r = 0; r < 4; r++) mx[r] = fmaxf(mx[r], acc[kt][r]);
    #pragma unroll
    for (int r = 0; r < 4; r++) {
        mx[r] = fmaxf(mx[r], __shfl_xor(mx[r], 1));
        mx[r] = fmaxf(mx[r], __shfl_xor(mx[r], 2));
        mx[r] = fmaxf(mx[r], __shfl_xor(mx[r], 4));
        mx[r] = fmaxf(mx[r], __shfl_xor(mx[r], 8));
    }
    float sm[4] = {0.f, 0.f, 0.f, 0.f};
    #pragma unroll
    for (int kt = 0; kt < 9; kt++)
        #pragma unroll
        for (int r = 0; r < 4; r++) {
            float e = __expf(acc[kt][r] - mx[r]);
            acc[kt][r] = e; sm[r] += e;
        }
    #pragma unroll
    for (int r = 0; r < 4; r++) {
        sm[r] += __shfl_xor(sm[r], 1);
        sm[r] += __shfl_xor(sm[r], 2);
        sm[r] += __shfl_xor(sm[r], 4);
        sm[r] += __shfl_xor(sm[r], 8);
        sm[r] = 1.0f / sm[r];
    }

    // ---- PV : O[16 x 32] per wave, K padded to 160; B-frags from vT ----
    bf16_t* ps = pscratch + s * 640;
    f32x4 oacc[2] = {{0.f,0.f,0.f,0.f}, {0.f,0.f,0.f,0.f}};
    for (int kc = 0; kc < 5; kc++) {
        #pragma unroll
        for (int tt = 0; tt < 2; tt++) {
            int kt = 2 * kc + tt;
            #pragma unroll
            for (int r = 0; r < 4; r++) {
                float pv = (kt < 9) ? acc[kt][r] * sm[r] : 0.f;
                ps[(4 * g + r) * 40 + tt * 16 + c] = f2b(pv);
            }
        }
        short8 ap = *(const short8*)(ps + c * 40 + 8 * g);
        #pragma unroll
        for (int dt = 0; dt < 2; dt++) {
            short8 bv = *(const short8*)(vT + (dt * 16 + c) * 168 + kc * 32 + 8 * g);
            oacc[dt] = __builtin_amdgcn_mfma_f32_16x16x32_bf16(ap, bv, oacc[dt], 0, 0, 0);
        }
    }
    #pragma unroll
    for (int dt = 0; dt < 2; dt++)
        #pragma unroll
        for (int r = 0; r < 4; r++)
            ob[tb + (16 * s + 4 * g + r) * 32 + dt * 16 + c] = f2b(oacc[dt][r]);
}

// ---------------------------------------------------------------------------
// Proj v2: A-frags direct from global o; W via DMA ping-pong. (r20 proven)
// ---------------------------------------------------------------------------
__global__ __launch_bounds__(256, 4) void proj_mfma_kernel(
    const bf16_t* __restrict__ ot, const float* __restrict__ x,
    const bf16_t* __restrict__ wp,  // [6 chunks][6144] swizzled
    const float* __restrict__ pb,
    float* __restrict__ xa)
{
    __shared__ bf16_t wbuf[2][6144];
    __shared__ float sbias[192];

    const int t = threadIdx.x, m0 = blockIdx.x * 64;
    const int l = t & 63, wv = t >> 6;
    const int c = l & 15, g = l >> 4;
    const int soff = wv * 512 + l * 8;

    #pragma unroll
    for (int i = 0; i < 3; i++)
        gload_lds16(wp + i * 2048 + soff, wbuf[0] + i * 2048 + soff);

    for (int v = t; v < 192; v += 256) sbias[v] = pb[v];

    // A-frags straight from global o (row c of wave's strip)
    const int ob_ = tiled_base(m0 + 16 * wv + c);
    short8 a[6];
    #pragma unroll
    for (int kc = 0; kc < 6; kc++)
        a[kc] = *(const short8*)(ot + ob_ + kc * 294912 + 8 * g);

    int xoff[4];
    #pragma unroll
    for (int r = 0; r < 4; r++) xoff[r] = src_off(m0 + 16 * wv + 4 * g + r);
    __syncthreads();                     // sbias staged

    for (int nc = 0; nc < 6; nc++) {
        const int p = nc & 1;
        if (nc < 5) {
            #pragma unroll
            for (int i = 0; i < 3; i++)
                gload_lds16(wp + (nc + 1) * 6144 + i * 2048 + soff,
                            wbuf[p ^ 1] + i * 2048 + soff);
            asm volatile("s_waitcnt vmcnt(3)");   // drain chunk nc (+older ops)
        } else {
            asm volatile("s_waitcnt vmcnt(0)");
        }
        asm volatile("" ::: "memory");
        __builtin_amdgcn_s_barrier();
        asm volatile("" ::: "memory");

        f32x4 acc[2] = {};
        #pragma unroll
        for (int kc = 0; kc < 6; kc++)
            #pragma unroll
            for (int ct = 0; ct < 2; ct++) {
                int r1 = ct * 16 + c;
                const bf16_t* pp = wbuf[p] + r1 * 192 + ((kc * 32 + 8 * g) ^ ((r1 & 7) << 3));
                short8 b = *(const short8*)pp;
                acc[ct] = __builtin_amdgcn_mfma_f32_16x16x32_bf16(a[kc], b, acc[ct], 0, 0, 0);
            }

        #pragma unroll
        for (int ct = 0; ct < 2; ct++) {
            int col = nc * 32 + ct * 16 + c;
            float bv = sbias[col];
            #pragma unroll
            for (int r = 0; r < 4; r++) {
                int off = xoff[r] + col;
                xa[off] = acc[ct][r] + bv + x[off];
            }
        }

        asm volatile("" ::: "memory");
        __builtin_amdgcn_s_barrier();   // wbuf[p] consumed before nc+2 DMA
        asm volatile("" ::: "memory");
    }
}

// ---------------------------------------------------------------------------
// Fused MLP v8b (r17 proven, byte-exact — confirmed local optimum over 7
// structural variants; v10 W2-dbuf regressed 191->207).
// ---------------------------------------------------------------------------
__global__ __launch_bounds__(256, 4) void mlp_kernel(
    const float* __restrict__ xa,
    const float* __restrict__ ln2w, const float* __restrict__ ln2b,
    const bf16_t* __restrict__ w1s,    // [24 chunks][6144] swizzled
    const float* __restrict__ b1,
    const bf16_t* __restrict__ w2s,    // [24 chunks][6144] permuted
    const float* __restrict__ b2,
    float* __restrict__ out)
{
    __shared__ bf16_t buf1[6144];   // W1 chunk: [32 fcol][192 k] (swizzled)
    __shared__ bf16_t buf2[6144];   // W2 chunk: [192 col][32 kl] (permuted)

    const int t = threadIdx.x, m0 = blockIdx.x * 64;
    const int l = t & 63, wv = t >> 6;
    const int c = l & 15, g = l >> 4;
    const int soff = wv * 512 + l * 8;   // DMA elem offset within 2048-seg

    // issue W1 chunk 0 DMA immediately; LN2 prologue hides its latency
    #pragma unroll
    for (int i = 0; i < 3; i++)
        gload_lds16(w1s + i * 2048 + soff, buf1 + i * 2048 + soff);

    // ---- LN2 on this lane's token, result held as FC1 B-frags in regs ----
    const float* xr = xa + (m0 + 16 * wv + c) * 192;
    float fa[6][8];
    float ss = 0.f, s2 = 0.f;
    #pragma unroll
    for (int kc = 0; kc < 6; kc++) {
        float4 v0 = *(const float4*)(xr + kc * 32 + 8 * g);
        float4 v1 = *(const float4*)(xr + kc * 32 + 8 * g + 4);
        fa[kc][0]=v0.x; fa[kc][1]=v0.y; fa[kc][2]=v0.z; fa[kc][3]=v0.w;
        fa[kc][4]=v1.x; fa[kc][5]=v1.y; fa[kc][6]=v1.z; fa[kc][7]=v1.w;
        ss += v0.x+v0.y+v0.z+v0.w + v1.x+v1.y+v1.z+v1.w;
        s2 += v0.x*v0.x+v0.y*v0.y+v0.z*v0.z+v0.w*v0.w
            + v1.x*v1.x+v1.y*v1.y+v1.z*v1.z+v1.w*v1.w;
    }
    ss += __shfl_xor(ss, 16); s2 += __shfl_xor(s2, 16);
    ss += __shfl_xor(ss, 32); s2 += __shfl_xor(s2, 32);
    float mu = ss * (1.f / 192.f);
    float rs = 1.0f / sqrtf(s2 * (1.f / 192.f) - mu * mu + 1e-5f);

    short8 xb[6];
    #pragma unroll
    for (int kc = 0; kc < 6; kc++) {
        float4 gw0 = *(const float4*)(ln2w + kc * 32 + 8 * g);
        float4 gw1 = *(const float4*)(ln2w + kc * 32 + 8 * g + 4);
        float4 gb0 = *(const float4*)(ln2b + kc * 32 + 8 * g);
        float4 gb1 = *(const float4*)(ln2b + kc * 32 + 8 * g + 4);
        union { bf16_t e[8]; short8 v; } u;
        u.e[0] = f2b((fa[kc][0]-mu)*rs*gw0.x + gb0.x);
        u.e[1] = f2b((fa[kc][1]-mu)*rs*gw0.y + gb0.y);
        u.e[2] = f2b((fa[kc][2]-mu)*rs*gw0.z + gb0.z);
        u.e[3] = f2b((fa[kc][3]-mu)*rs*gw0.w + gb0.w);
        u.e[4] = f2b((fa[kc][4]-mu)*rs*gw1.x + gb1.x);
        u.e[5] = f2b((fa[kc][5]-mu)*rs*gw1.y + gb1.y);
        u.e[6] = f2b((fa[kc][6]-mu)*rs*gw1.z + gb1.z);
        u.e[7] = f2b((fa[kc][7]-mu)*rs*gw1.w + gb1.w);
        xb[kc] = u.v;
    }

    f32x4 acc2[12] = {};

    for (int nc = 0; nc < 24; nc++) {
        // bias loads FIRST (older than W2 DMA -> waiting them won't drain it)
        float4 bvv[2];
        #pragma unroll
        for (int ctA = 0; ctA < 2; ctA++)
            bvv[ctA] = *(const float4*)(b1 + nc * 32 + ctA * 16 + 4 * g);

        // issue W2 chunk nc DMA -> buf2 (in flight during FC1)
        #pragma unroll
        for (int i = 0; i < 3; i++)
            gload_lds16(w2s + nc * 6144 + i * 2048 + soff, buf2 + i * 2048 + soff);

        asm volatile("s_waitcnt vmcnt(5)");     // drain 3 W1 (oldest)
        asm volatile("" ::: "memory");
        __builtin_amdgcn_s_barrier();
        asm volatile("" ::: "memory");

        // ---- FC1 swapped: D[fcol-local][token], A from swizzled buf1 ----
        f32x4 acc1[2] = {};
        #pragma unroll
        for (int kc = 0; kc < 6; kc++)
            #pragma unroll
            for (int ctA = 0; ctA < 2; ctA++) {
                int r1 = ctA * 16 + c;
                const bf16_t* p = buf1 + r1 * 192 + ((kc * 32 + 8 * g) ^ ((r1 & 7) << 3));
                short8 aw = *(const short8*)p;
                acc1[ctA] = __builtin_amdgcn_mfma_f32_16x16x32_bf16(aw, xb[kc], acc1[ctA], 0, 0, 0);
            }

        // ---- bias + fast GELU -> FC2 A-frags in regs ----
        short4v a2[2];
        #pragma unroll
        for (int ctA = 0; ctA < 2; ctA++) {
            union { bf16_t e[4]; short4v v; } u;
            u.e[0] = f2b(gelu_fast(acc1[ctA][0] + bvv[ctA].x));
            u.e[1] = f2b(gelu_fast(acc1[ctA][1] + bvv[ctA].y));
            u.e[2] = f2b(gelu_fast(acc1[ctA][2] + bvv[ctA].z));
            u.e[3] = f2b(gelu_fast(acc1[ctA][3] + bvv[ctA].w));
            a2[ctA] = u.v;
        }

        asm volatile("" ::: "memory");
        __builtin_amdgcn_s_barrier();           // all waves done reading buf1
        asm volatile("" ::: "memory");

        // issue W1 chunk nc+1 DMA -> buf1 (in flight during FC2)
        if (nc < 23) {
            #pragma unroll
            for (int i = 0; i < 3; i++)
                gload_lds16(w1s + (nc + 1) * 6144 + i * 2048 + soff,
                            buf1 + i * 2048 + soff);
            asm volatile("s_waitcnt vmcnt(3)"); // W2 chunk nc landed; W1next in flight
        } else {
            asm volatile("s_waitcnt vmcnt(0)");
        }
        asm volatile("" ::: "memory");
        __builtin_amdgcn_s_barrier();
        asm volatile("" ::: "memory");

        // ---- FC2 partial: one b128 per ctB covers both ctA frags ----
        #pragma unroll
        for (int ctB = 0; ctB < 12; ctB++) {
            const bf16_t* p = buf2 + (ctB * 16 + c) * 32 + g * 8;
            union { short4v h[2]; short8 v; } bb;
            bb.v = *(const short8*)p;
            acc2[ctB] = MFMA16(a2[0], bb.h[0], acc2[ctB]);
            acc2[ctB] = MFMA16(a2[1], bb.h[1], acc2[ctB]);
        }

        asm volatile("" ::: "memory");
        __builtin_amdgcn_s_barrier();           // buf2 consumed before next stage
        asm volatile("" ::: "memory");
    }

    // ---- epilogue: out += fc2 + bias (out holds xa) ----
    #pragma unroll
    for (int ctB = 0; ctB < 12; ctB++) {
        int col = ctB * 16 + c;
        float bv = b2[col];
        #pragma unroll
        for (int r = 0; r < 4; r++) {
            int off = (m0 + 16 * wv + 4 * g + r) * 192 + col;
            out[off] = acc2[ctB][r] + bv + out[off];
        }
    }
}

// ---------------------------------------------------------------------------
extern "C" void kernel_launch(void* const* d_in, const int* in_sizes, int n_in,
                              void* d_out, int out_size, void* d_ws, size_t ws_size,
                              hipStream_t stream)
{
    const float* x      = (const float*)d_in[0];
    const float* ln1w   = (const float*)d_in[1];
    const float* ln1b   = (const float*)d_in[2];
    const float* qkvw   = (const float*)d_in[3];
    const float* qkvb   = (const float*)d_in[4];
    const float* projw  = (const float*)d_in[5];
    const float* projb  = (const float*)d_in[6];
    const float* biast  = (const float*)d_in[7];
    const float* ln2w   = (const float*)d_in[8];
    const float* ln2b   = (const float*)d_in[9];
    const float* fc1w   = (const float*)d_in[10];
    const float* fc1b   = (const float*)d_in[11];
    const float* fc2w   = (const float*)d_in[12];
    const float* fc2b   = (const float*)d_in[13];
    float* out = (float*)d_out;

    // ws layout (bytes): q 53.1MB | K-padded 70.8MB | v 53.1MB | weights | btT
    const size_t SLOTB = 53084160;      // 138240*192 bf16 bytes
    const size_t KSLOT = 70778880;      // 5760*6144 bf16 bytes (padded K)
    char* base = (char*)d_ws;
    bf16_t* qbuf = (bf16_t*)(base);
    bf16_t* kbuf = (bf16_t*)(base + SLOTB);
    bf16_t* vbuf = (bf16_t*)(base + SLOTB + KSLOT);
    bf16_t* wq   = (bf16_t*)(base + 2 * SLOTB + KSLOT);   // [18][6144]
    bf16_t* wpp  = wq   + 110592;                         // [6][6144]
    bf16_t* w1s  = wpp  + 36864;                          // [24][6144]
    bf16_t* w2s  = w1s  + 147456;                         // [24][6144]
    float*  btT  = (float*)(w2s + 147456);                // [384][3584] padded

    prep_kernel<<<7104, 256, 0, stream>>>(qkvw, projw, fc1w, fc2w, biast,
                                          wq, wpp, w1s, w2s, btT);

    qkv_mfma_kernel<<<2160, 256, 0, stream>>>(x, ln1w, ln1b, wq, qkvb, qbuf, kbuf, vbuf);
    attn_kernel<<<5760, 576, 0, stream>>>(qbuf, kbuf, vbuf, btT, qbuf);
    proj_mfma_kernel<<<2160, 256, 0, stream>>>(qbuf, x, wpp, projb, out);
    mlp_kernel<<<2160, 256, 0, stream>>>(out, ln2w, ln2b, w1s, fc1b, w2s, fc2b, out);
}